// Round 1
// baseline (576.320 us; speedup 1.0000x reference)
//
#include <hip/hip_runtime.h>

// FPN_AAR: FPN lateral/top-down + AdaptiveAngleConv (5 rotated 3x3) + SK fusion.
// Strategy: rotations are permutations of one kernel -> compute 9 tap planes
// S[s] = W[:,:,s] @ lat (one GEMM, M=2304,K=256,N=HW), then each rotation is a
// 9-term shifted gather of the planes. 5x FLOP reduction vs direct conv.
// All GEMMs: bf16 MFMA 16x16x32, 128x128 tile, 4 waves, padded LDS (stride 40).

typedef unsigned short u16;
typedef unsigned int   u32;
typedef __bf16 bf16x8 __attribute__((ext_vector_type(8)));
typedef float  f32x4  __attribute__((ext_vector_type(4)));
typedef u16    u16x8  __attribute__((ext_vector_type(8)));
typedef u16    u16x4  __attribute__((ext_vector_type(4)));

__device__ __forceinline__ u16 f2b(float f) {  // f32 -> bf16 RNE
  u32 u = __builtin_bit_cast(u32, f);
  return (u16)((u + 0x7fffu + ((u >> 16) & 1u)) >> 16);
}
__device__ __forceinline__ float b2f(u16 h) {
  u32 u = ((u32)h) << 16;
  return __builtin_bit_cast(float, u);
}

__constant__ int c_rot[5][9] = {
  {0,1,2,3,4,5,6,7,8},
  {3,0,1,6,4,2,7,8,5},
  {6,3,0,7,4,1,8,5,2},
  {7,6,3,8,4,0,5,2,1},
  {8,7,6,5,4,3,2,1,0}};

// ---------------- utility kernels ----------------
__global__ void k_cvt(const float* __restrict__ in, u16* __restrict__ out, int n) {
  int i = blockIdx.x * 256 + threadIdx.x;
  if (i < n) out[i] = f2b(in[i]);
}

// in: f32 [C][P] -> out: bf16 [P][C]   (32x32 tiles via LDS)
__global__ __launch_bounds__(256) void k_transpose(const float* __restrict__ in,
                                                   u16* __restrict__ out, int C, int P) {
  __shared__ u16 t[32][33];
  int tx = threadIdx.x, ty = threadIdx.y;
  int p0 = blockIdx.x * 32, c0 = blockIdx.y * 32;
#pragma unroll
  for (int j = 0; j < 4; ++j)
    t[ty + 8 * j][tx] = f2b(in[(long)(c0 + ty + 8 * j) * P + p0 + tx]);
  __syncthreads();
#pragma unroll
  for (int j = 0; j < 4; ++j)
    out[(long)(p0 + ty + 8 * j) * C + c0 + tx] = t[tx][ty + 8 * j];
}

// aac_w level slice f32 [256][256][9] -> W9 bf16 [(t*256+oc)][ic]  (K-contiguous A)
__global__ __launch_bounds__(256) void k_prep_w9(const float* __restrict__ w,
                                                 u16* __restrict__ out) {
  int idx = blockIdx.x * 256 + threadIdx.x;  // oc*256+ic, 65536 total
  const float* src = w + (long)idx * 9;
  int oc = idx >> 8, ic = idx & 255;
  float v[9];
#pragma unroll
  for (int t = 0; t < 9; ++t) v[t] = src[t];
#pragma unroll
  for (int t = 0; t < 9; ++t) out[(long)((t << 8) + oc) * 256 + ic] = f2b(v[t]);
}

// dst bf16 [HW][256] += nearest-2x-up(src bf16 [HW/4][256])
__global__ void k_ups_add(u16* __restrict__ dst, const u16* __restrict__ src, int W, int HW) {
  int idx = blockIdx.x * 256 + threadIdx.x;   // HW*32 threads, 8 ch each
  int p = idx >> 5, c8 = (idx & 31) << 3;
  if (p >= HW) return;
  int y = p / W, x = p - y * W;
  int sp = (y >> 1) * (W >> 1) + (x >> 1);
  u16x8 d = *(const u16x8*)(dst + (long)p * 256 + c8);
  u16x8 s = *(const u16x8*)(src + (long)sp * 256 + c8);
  u16x8 o;
#pragma unroll
  for (int e = 0; e < 8; ++e) o[e] = f2b(b2f(d[e]) + b2f(s[e]));
  *(u16x8*)(dst + (long)p * 256 + c8) = o;
}

// ---------------- bf16 MFMA GEMM ----------------
// C = A(bf16 [M][K]) * B^T-layout(bf16 [N][K]).
// MODE 0: store C bf16 [M][N] (ldc=N), no bias.
// MODE 1: store C transposed bf16 [N][ldc] with f32 bias[M]   (produces latT[p][oc]).
template <int MODE>
__global__ __launch_bounds__(256) void k_gemm(const u16* __restrict__ A,
                                              const u16* __restrict__ B,
                                              u16* __restrict__ C,
                                              const float* __restrict__ bias,
                                              int M, int N, int K, int ldc) {
  __shared__ alignas(16) u16 As[128 * 40];  // row stride 40 (=80B) -> conflict-lite frags
  __shared__ alignas(16) u16 Bs[128 * 40];
  const int tid = threadIdx.x;
  const int wid = tid >> 6, lane = tid & 63;
  const int wr = wid >> 1, wc = wid & 1;          // 2x2 waves, each 64x64
  const int m0 = blockIdx.y * 128, n0 = blockIdx.x * 128;
  const int lr = lane & 15, lk = lane >> 4;

  f32x4 acc[4][4] = {};

  const int r0 = tid >> 2, kc0 = (tid & 3) * 8;   // staging: 4 lanes per row
  const int r1 = r0 + 64;
  const u16* Ag = A + (long)m0 * K + kc0;
  const u16* Bg = B + (long)n0 * K + kc0;

  u16x8 a0, a1, b0, b1;
  auto load_tile = [&](int kt) {
    a0 = *(const u16x8*)(Ag + (long)r0 * K + kt);
    a1 = *(const u16x8*)(Ag + (long)r1 * K + kt);
    b0 = *(const u16x8*)(Bg + (long)r0 * K + kt);
    b1 = *(const u16x8*)(Bg + (long)r1 * K + kt);
  };
  load_tile(0);
  for (int kt = 0; kt < K; kt += 32) {
    *(u16x8*)(As + r0 * 40 + kc0) = a0;
    *(u16x8*)(As + r1 * 40 + kc0) = a1;
    *(u16x8*)(Bs + r0 * 40 + kc0) = b0;
    *(u16x8*)(Bs + r1 * 40 + kc0) = b1;
    __syncthreads();
    if (kt + 32 < K) load_tile(kt + 32);          // prefetch next tile during MFMA
    bf16x8 af[4], bfr[4];
#pragma unroll
    for (int m = 0; m < 4; ++m)
      af[m] = *(const bf16x8*)(As + (wr * 64 + m * 16 + lr) * 40 + lk * 8);
#pragma unroll
    for (int n = 0; n < 4; ++n)
      bfr[n] = *(const bf16x8*)(Bs + (wc * 64 + n * 16 + lr) * 40 + lk * 8);
#pragma unroll
    for (int m = 0; m < 4; ++m)
#pragma unroll
      for (int n = 0; n < 4; ++n)
        acc[m][n] = __builtin_amdgcn_mfma_f32_16x16x32_bf16(af[m], bfr[n], acc[m][n], 0, 0, 0);
    __syncthreads();
  }

  if constexpr (MODE == 0) {
#pragma unroll
    for (int m = 0; m < 4; ++m) {
      int row = m0 + wr * 64 + m * 16 + lk * 4;   // C/D: col=lane&15, row=(lane>>4)*4+i
#pragma unroll
      for (int n = 0; n < 4; ++n) {
        int col = n0 + wc * 64 + n * 16 + lr;
#pragma unroll
        for (int i = 0; i < 4; ++i)
          C[(long)(row + i) * ldc + col] = f2b(acc[m][n][i]);
      }
    }
  } else {
#pragma unroll
    for (int m = 0; m < 4; ++m) {
      int row = m0 + wr * 64 + m * 16 + lk * 4;
      f32x4 bv = *(const f32x4*)(bias + row);
#pragma unroll
      for (int n = 0; n < 4; ++n) {
        int col = n0 + wc * 64 + n * 16 + lr;
        u16x4 o;
#pragma unroll
        for (int i = 0; i < 4; ++i) o[i] = f2b(acc[m][n][i] + bv[i]);
        *(u16x4*)(C + (long)col * ldc + row) = o;  // 8B packed transposed store
      }
    }
  }
}

// ---------------- gather + BN + ReLU + channel-sum ----------------
// Block = (channel c, 4 output rows). Stages 9 planes x 6 rows (+zero border)
// of S into LDS as f32, then each rotation = 9 shifted adds from LDS.
__global__ __launch_bounds__(256) void k_gather(const u16* __restrict__ S,
                                                u16* __restrict__ feas,
                                                float* __restrict__ fea_s,
                                                const float* __restrict__ aac_b,
                                                const float* __restrict__ bn_g,
                                                const float* __restrict__ bn_b,
                                                const float* __restrict__ bn_m,
                                                const float* __restrict__ bn_v,
                                                int W, int H) {
  __shared__ float sm[9][6][130];   // [plane][row y0-1..y0+4][col x=-1..W]
  __shared__ float red[4];
  const int tid = threadIdx.x;
  const int c = blockIdx.y;
  const int y0 = blockIdx.x * 4;
  const int HW = W * H;
  if (tid < 54) { int s = tid / 6, r = tid - s * 6; sm[s][r][0] = 0.f; sm[s][r][W + 1] = 0.f; }
  const int w8 = W >> 3;
  for (int idx = tid; idx < 54 * w8; idx += 256) {
    int s = idx / (6 * w8);
    int rem = idx - s * (6 * w8);
    int r = rem / w8, x8 = rem - r * w8;
    int y = y0 - 1 + r;
    float* drow = &sm[s][r][1 + x8 * 8];
    if (y >= 0 && y < H) {
      u16x8 v = *(const u16x8*)(S + (long)(s * 256 + c) * HW + (long)y * W + x8 * 8);
#pragma unroll
      for (int e = 0; e < 8; ++e) drow[e] = b2f(v[e]);
    } else {
#pragma unroll
      for (int e = 0; e < 8; ++e) drow[e] = 0.f;
    }
  }
  __syncthreads();

  float sc[5], sh[5];
#pragma unroll
  for (int m = 0; m < 5; ++m) {
    float g = bn_g[m * 256 + c], bb = bn_b[m * 256 + c];
    float mu = bn_m[m * 256 + c], vv = bn_v[m * 256 + c];
    float s = g * rsqrtf(vv + 1e-5f);
    sc[m] = s; sh[m] = bb - mu * s;
  }
  const float ab = aac_b[c];
  float lsum = 0.f;
  for (int pi = tid; pi < 4 * W; pi += 256) {
    int ro = pi / W, x = pi - ro * W;
    int y = y0 + ro;
    float val[5] = {ab, ab, ab, ab, ab};
#pragma unroll
    for (int t = 0; t < 9; ++t) {
      int dy = t / 3, dx = t - dy * 3;
#pragma unroll
      for (int m = 0; m < 5; ++m)
        val[m] += sm[c_rot[m][t]][ro + dy][x + dx];
    }
#pragma unroll
    for (int m = 0; m < 5; ++m) {
      float f = fmaxf(val[m] * sc[m] + sh[m], 0.f);
      feas[(long)(m * 256 + c) * HW + (long)y * W + x] = f2b(f);
      lsum += f;
    }
  }
#pragma unroll
  for (int off = 32; off > 0; off >>= 1) lsum += __shfl_down(lsum, off);
  if ((tid & 63) == 0) red[tid >> 6] = lsum;
  __syncthreads();
  if (tid == 0) atomicAdd(&fea_s[c], red[0] + red[1] + red[2] + red[3]);
}

// ---------------- tiny FC + softmax attention (1 block / level) ----------------
__global__ __launch_bounds__(256) void k_fc_att(const float* __restrict__ fea_s, float inv_hw,
                                                const float* __restrict__ fc_w,
                                                const float* __restrict__ fc_b,
                                                const float* __restrict__ fcs_w,
                                                const float* __restrict__ fcs_b,
                                                float* __restrict__ att) {
  __shared__ float ss[256];
  __shared__ float zs[128];
  int tid = threadIdx.x;
  ss[tid] = fea_s[tid] * inv_hw;
  __syncthreads();
  if (tid < 128) {
    float z = fc_b[tid];
    const float* wr = fc_w + tid * 256;
    for (int cc = 0; cc < 256; ++cc) z += ss[cc] * wr[cc];
    zs[tid] = z;
  }
  __syncthreads();
  float lg[5];
#pragma unroll
  for (int m = 0; m < 5; ++m) {
    const float* wr = fcs_w + (m * 256 + tid) * 128;
    float l = fcs_b[m * 256 + tid];
    for (int d = 0; d < 128; ++d) l += zs[d] * wr[d];
    lg[m] = l;
  }
  float mx = lg[0];
#pragma unroll
  for (int m = 1; m < 5; ++m) mx = fmaxf(mx, lg[m]);
  float se = 0.f;
#pragma unroll
  for (int m = 0; m < 5; ++m) { lg[m] = __expf(lg[m] - mx); se += lg[m]; }
  float inv = 1.f / se;
#pragma unroll
  for (int m = 0; m < 5; ++m) att[m * 256 + tid] = lg[m] * inv;
}

// ---------------- weighted combine ----------------
__global__ __launch_bounds__(256) void k_combine(const u16* __restrict__ feas,
                                                 const float* __restrict__ att,
                                                 float* __restrict__ out, int HW) {
  int idx = blockIdx.x * 256 + threadIdx.x;
  int hw8 = HW >> 3;
  int c = idx / hw8, p = (idx - c * hw8) << 3;
  float a[5];
#pragma unroll
  for (int m = 0; m < 5; ++m) a[m] = att[m * 256 + c];
  float o[8] = {};
#pragma unroll
  for (int m = 0; m < 5; ++m) {
    u16x8 v = *(const u16x8*)(feas + (long)(m * 256 + c) * HW + p);
#pragma unroll
    for (int e = 0; e < 8; ++e) o[e] += a[m] * b2f(v[e]);
  }
  float* op = out + (long)c * HW + p;
  f32x4 v0 = {o[0], o[1], o[2], o[3]};
  f32x4 v1 = {o[4], o[5], o[6], o[7]};
  *(f32x4*)op = v0;
  *(f32x4*)(op + 4) = v1;
}

// ---------------- host ----------------
extern "C" void kernel_launch(void* const* d_in, const int* in_sizes, int n_in,
                              void* d_out, int out_size, void* d_ws, size_t ws_size,
                              hipStream_t stream) {
  (void)n_in; (void)out_size; (void)ws_size;
  static const int HWs[4] = {16384, 4096, 1024, 256};
  static const int Ws[4]  = {128, 64, 32, 16};
  static const int Hs[4]  = {128, 64, 32, 16};
  static const int Cin[4] = {256, 512, 1024, 2048};
  static const long out_off[4] = {0, 4194304, 5242880, 5505024};

  // setup_inputs dict order is interleaved x0,lw0,x1,lw1,...; defensively
  // detect signature order (x0..x3,lw0..lw3) via in_sizes[1].
  int xi[4], li[4];
  if (in_sizes[1] == 256 * 256) {
    for (int i = 0; i < 4; ++i) { xi[i] = 2 * i; li[i] = 2 * i + 1; }
  } else {
    for (int i = 0; i < 4; ++i) { xi[i] = i; li[i] = 4 + i; }
  }
  const float *x[4], *lw[4];
  for (int i = 0; i < 4; ++i) { x[i] = (const float*)d_in[xi[i]]; lw[i] = (const float*)d_in[li[i]]; }
  const float* lb    = (const float*)d_in[8];
  const float* aac_w = (const float*)d_in[9];
  const float* aac_b = (const float*)d_in[10];
  const float* bn_g  = (const float*)d_in[11];
  const float* bn_b  = (const float*)d_in[12];
  const float* bn_m  = (const float*)d_in[13];
  const float* bn_v  = (const float*)d_in[14];
  const float* fc_w  = (const float*)d_in[15];
  const float* fc_b  = (const float*)d_in[16];
  const float* fcs_w = (const float*)d_in[17];
  const float* fcs_b = (const float*)d_in[18];

  // workspace carve (~144 MB total)
  char* wp = (char*)d_ws;
  auto carve = [&](size_t bytes) { char* p = wp; wp += (bytes + 255) & ~(size_t)255; return p; };
  u16* xT[4];   for (int i = 0; i < 4; ++i) xT[i]   = (u16*)carve((size_t)HWs[i] * Cin[i] * 2);
  u16* lwb[4];  for (int i = 0; i < 4; ++i) lwb[i]  = (u16*)carve((size_t)256 * Cin[i] * 2);
  u16* latT[4]; for (int i = 0; i < 4; ++i) latT[i] = (u16*)carve((size_t)HWs[i] * 256 * 2);
  u16* W9[4];   for (int i = 0; i < 4; ++i) W9[i]   = (u16*)carve((size_t)2304 * 256 * 2);
  u16* Sb     = (u16*)carve((size_t)2304 * 16384 * 2);
  u16* feas   = (u16*)carve((size_t)5 * 256 * 16384 * 2);
  float* fea_s = (float*)carve(4 * 256 * 4);
  float* att   = (float*)carve(4 * 5 * 256 * 4);

  hipMemsetAsync(fea_s, 0, 4 * 256 * 4, stream);

  // weight/input prep
  for (int i = 0; i < 4; ++i)
    k_cvt<<<(256 * Cin[i] + 255) / 256, 256, 0, stream>>>(lw[i], lwb[i], 256 * Cin[i]);
  for (int i = 0; i < 4; ++i)
    k_transpose<<<dim3(HWs[i] / 32, Cin[i] / 32), dim3(32, 8), 0, stream>>>(x[i], xT[i], Cin[i], HWs[i]);
  for (int i = 0; i < 4; ++i)
    k_prep_w9<<<256, 256, 0, stream>>>(aac_w + (long)i * 256 * 256 * 9, W9[i]);

  // lateral 1x1 convs (stored transposed + bias) and top-down pathway
  for (int i = 3; i >= 0; --i) {
    k_gemm<1><<<dim3(HWs[i] / 128, 2), 256, 0, stream>>>(lwb[i], xT[i], latT[i], lb + i * 256,
                                                         256, HWs[i], Cin[i], 256);
    if (i < 3)
      k_ups_add<<<HWs[i] / 8, 256, 0, stream>>>(latT[i], latT[i + 1], Ws[i], HWs[i]);
  }

  // per level: 9-plane GEMM -> gather/BN/ReLU/mean -> FC+softmax -> combine
  for (int i = 0; i < 4; ++i) {
    k_gemm<0><<<dim3(HWs[i] / 128, 18), 256, 0, stream>>>(W9[i], latT[i], Sb, nullptr,
                                                          2304, HWs[i], 256, HWs[i]);
    k_gather<<<dim3(Hs[i] / 4, 256), 256, 0, stream>>>(Sb, feas, fea_s + i * 256,
        aac_b + i * 256, bn_g + i * 1280, bn_b + i * 1280, bn_m + i * 1280, bn_v + i * 1280,
        Ws[i], Hs[i]);
    k_fc_att<<<1, 256, 0, stream>>>(fea_s + i * 256, 1.0f / HWs[i],
        fc_w + (long)i * 128 * 256, fc_b + i * 128,
        fcs_w + (long)i * 5 * 256 * 128, fcs_b + i * 5 * 256, att + i * 5 * 256);
    k_combine<<<HWs[i] / 8, 256, 0, stream>>>(feas, att + i * 5 * 256,
        (float*)d_out + out_off[i], HWs[i]);
  }
}

// Round 2
// 490.555 us; speedup vs baseline: 1.1748x; 1.1748x over previous
//
#include <hip/hip_runtime.h>

// FPN_AAR: FPN lateral/top-down + AdaptiveAngleConv (5 rotated 3x3) + SK fusion.
// Rotations are permutations of one kernel -> compute 9 tap planes
// S[s] = W[:,:,s] @ lat (one GEMM), then each rotation is a 9-term shifted
// gather of the planes (5x FLOP reduction vs direct conv).
// R2: global_load_lds GEMM (m97 structure), vectorized conflict-free gather,
//     batched prep kernels, multi-block fc_att.

typedef unsigned short u16;
typedef unsigned int   u32;
typedef __bf16 bf16x8 __attribute__((ext_vector_type(8)));
typedef float  f32x4  __attribute__((ext_vector_type(4)));
typedef u16    u16x8  __attribute__((ext_vector_type(8)));
typedef u16    u16x4  __attribute__((ext_vector_type(4)));

__device__ __forceinline__ u16 f2b(float f) {  // f32 -> bf16 RNE
  u32 u = __builtin_bit_cast(u32, f);
  return (u16)((u + 0x7fffu + ((u >> 16) & 1u)) >> 16);
}
__device__ __forceinline__ float b2f(u16 h) {
  u32 u = ((u32)h) << 16;
  return __builtin_bit_cast(float, u);
}

constexpr int ROT[5][9] = {
  {0,1,2,3,4,5,6,7,8},
  {3,0,1,6,4,2,7,8,5},
  {6,3,0,7,4,1,8,5,2},
  {7,6,3,8,4,0,5,2,1},
  {8,7,6,5,4,3,2,1,0}};

__device__ __forceinline__ void glds16(const u16* g, u16* l) {
  __builtin_amdgcn_global_load_lds((const __attribute__((address_space(1))) void*)g,
                                   (__attribute__((address_space(3))) void*)l, 16, 0, 0);
}

// ---------------- batched prep kernels ----------------
__global__ __launch_bounds__(256) void k_cvt_all(const float* __restrict__ a0,
    const float* __restrict__ a1, const float* __restrict__ a2, const float* __restrict__ a3,
    u16* __restrict__ o0, u16* __restrict__ o1, u16* __restrict__ o2, u16* __restrict__ o3) {
  int i = blockIdx.x * 256 + threadIdx.x;  // 983040 total
  const float* src; u16* dst; int off;
  if (i < 65536)       { src = a0; dst = o0; off = i; }
  else if (i < 196608) { src = a1; dst = o1; off = i - 65536; }
  else if (i < 458752) { src = a2; dst = o2; off = i - 196608; }
  else                 { src = a3; dst = o3; off = i - 458752; }
  dst[off] = f2b(src[off]);
}

// f32 [C][P] -> bf16 [P][C], all 4 levels in one launch (7680 blocks)
__global__ __launch_bounds__(256) void k_transpose_all(
    const float* __restrict__ x0, const float* __restrict__ x1,
    const float* __restrict__ x2, const float* __restrict__ x3,
    u16* __restrict__ t0p, u16* __restrict__ t1p,
    u16* __restrict__ t2p, u16* __restrict__ t3p) {
  __shared__ u16 t[32][33];
  int b = blockIdx.x, lvl, local;
  if (b < 4096)      { lvl = 0; local = b; }
  else if (b < 6144) { lvl = 1; local = b - 4096; }
  else if (b < 7168) { lvl = 2; local = b - 6144; }
  else               { lvl = 3; local = b - 7168; }
  const float* src = lvl == 0 ? x0 : lvl == 1 ? x1 : lvl == 2 ? x2 : x3;
  u16* dst = lvl == 0 ? t0p : lvl == 1 ? t1p : lvl == 2 ? t2p : t3p;
  const int P = 16384 >> (2 * lvl);
  const int C = 256 << lvl;
  const int pb = P >> 5;
  int bx = local & (pb - 1), by = local / pb;
  int p0 = bx * 32, c0 = by * 32;
  int tx = threadIdx.x, ty = threadIdx.y;
#pragma unroll
  for (int j = 0; j < 4; ++j)
    t[ty + 8 * j][tx] = f2b(src[(long)(c0 + ty + 8 * j) * P + p0 + tx]);
  __syncthreads();
#pragma unroll
  for (int j = 0; j < 4; ++j)
    dst[(long)(p0 + ty + 8 * j) * C + c0 + tx] = t[tx][ty + 8 * j];
}

// aac_w f32 [4][256][256][9] -> per level W9 bf16 [(t*256+oc)][ic]
__global__ __launch_bounds__(256) void k_prep_w9_all(const float* __restrict__ w,
    u16* __restrict__ o0, u16* __restrict__ o1, u16* __restrict__ o2, u16* __restrict__ o3) {
  int gid = blockIdx.x * 256 + threadIdx.x;   // 262144
  int lvl = gid >> 16, idx = gid & 65535;
  u16* out = lvl == 0 ? o0 : lvl == 1 ? o1 : lvl == 2 ? o2 : o3;
  const float* src = w + (long)lvl * 589824 + (long)idx * 9;
  int oc = idx >> 8, ic = idx & 255;
  float v[9];
#pragma unroll
  for (int t = 0; t < 9; ++t) v[t] = src[t];
#pragma unroll
  for (int t = 0; t < 9; ++t) out[(long)((t << 8) + oc) * 256 + ic] = f2b(v[t]);
}

// dst bf16 [HW][256] += nearest-2x-up(src bf16 [HW/4][256])
__global__ void k_ups_add(u16* __restrict__ dst, const u16* __restrict__ src, int W, int HW) {
  int idx = blockIdx.x * 256 + threadIdx.x;
  int p = idx >> 5, c8 = (idx & 31) << 3;
  if (p >= HW) return;
  int y = p / W, x = p - y * W;
  int sp = (y >> 1) * (W >> 1) + (x >> 1);
  u16x8 d = *(const u16x8*)(dst + (long)p * 256 + c8);
  u16x8 s = *(const u16x8*)(src + (long)sp * 256 + c8);
  u16x8 o;
#pragma unroll
  for (int e = 0; e < 8; ++e) o[e] = f2b(b2f(d[e]) + b2f(s[e]));
  *(u16x8*)(dst + (long)p * 256 + c8) = o;
}

// ---------------- bf16 MFMA GEMM (m97 structure: global_load_lds, linear LDS) ----
// C = A(bf16 [M][K]) * B^T-layout(bf16 [N][K]).
// MODE 0: C bf16 [M][N] (ldc=N). MODE 1: C transposed bf16 [N][ldc] + f32 bias[M].
template <int MODE>
__global__ __launch_bounds__(256) void k_gemm(const u16* __restrict__ A,
                                              const u16* __restrict__ B,
                                              u16* __restrict__ C,
                                              const float* __restrict__ bias,
                                              int M, int N, int K, int ldc) {
  __shared__ alignas(16) u16 As[128 * 32];   // linear [row][32] (64B rows)
  __shared__ alignas(16) u16 Bs[128 * 32];
  const int tid = threadIdx.x;
  const int wid = tid >> 6, lane = tid & 63;
  const int wr = wid >> 1, wc = wid & 1;
  const int m0 = blockIdx.y * 128, n0 = blockIdx.x * 128;
  const int lr = lane & 15, lk = lane >> 4;

  f32x4 acc[4][4] = {};

  // staging: inst t in [0,8) covers LDS rows [t*16, t*16+16); wave issues t=2*wid, 2*wid+1
  const int t0 = wid * 2;
  const int srow = lane >> 2;          // 0..15
  const int scol = (lane & 3) * 8;     // bf16 col
  const u16* gA0 = A + (long)(m0 + t0 * 16 + srow) * K + scol;
  const u16* gA1 = A + (long)(m0 + t0 * 16 + 16 + srow) * K + scol;
  const u16* gB0 = B + (long)(n0 + t0 * 16 + srow) * K + scol;
  const u16* gB1 = B + (long)(n0 + t0 * 16 + 16 + srow) * K + scol;
  u16* lA0 = As + t0 * 512;            // wave-uniform bases (1KB apart)
  u16* lA1 = As + t0 * 512 + 512;
  u16* lB0 = Bs + t0 * 512;
  u16* lB1 = Bs + t0 * 512 + 512;

  for (int kt = 0; kt < K; kt += 32) {
    glds16(gA0 + kt, lA0);
    glds16(gA1 + kt, lA1);
    glds16(gB0 + kt, lB0);
    glds16(gB1 + kt, lB1);
    __syncthreads();                   // compiler drains vmcnt before barrier
    bf16x8 af[4], bfr[4];
#pragma unroll
    for (int m = 0; m < 4; ++m)
      af[m] = *(const bf16x8*)(As + (wr * 64 + m * 16 + lr) * 32 + lk * 8);
#pragma unroll
    for (int n = 0; n < 4; ++n)
      bfr[n] = *(const bf16x8*)(Bs + (wc * 64 + n * 16 + lr) * 32 + lk * 8);
#pragma unroll
    for (int m = 0; m < 4; ++m)
#pragma unroll
      for (int n = 0; n < 4; ++n)
        acc[m][n] = __builtin_amdgcn_mfma_f32_16x16x32_bf16(af[m], bfr[n], acc[m][n], 0, 0, 0);
    __syncthreads();
  }

  if constexpr (MODE == 0) {
#pragma unroll
    for (int m = 0; m < 4; ++m) {
      int row = m0 + wr * 64 + m * 16 + lk * 4;   // C/D: col=lane&15, row=(lane>>4)*4+i
#pragma unroll
      for (int n = 0; n < 4; ++n) {
        int col = n0 + wc * 64 + n * 16 + lr;
#pragma unroll
        for (int i = 0; i < 4; ++i)
          C[(long)(row + i) * ldc + col] = f2b(acc[m][n][i]);
      }
    }
  } else {
#pragma unroll
    for (int m = 0; m < 4; ++m) {
      int row = m0 + wr * 64 + m * 16 + lk * 4;
      f32x4 bv = *(const f32x4*)(bias + row);
#pragma unroll
      for (int n = 0; n < 4; ++n) {
        int col = n0 + wc * 64 + n * 16 + lr;
        u16x4 o;
#pragma unroll
        for (int i = 0; i < 4; ++i) o[i] = f2b(acc[m][n][i] + bv[i]);
        *(u16x4*)(C + (long)col * ldc + row) = o;
      }
    }
  }
}

// ---------------- gather + BN + ReLU + channel-sum (vectorized, per-level) ------
// Block = (channel c, RB output rows), 128 threads. Stage 9 planes x (RB+2) rows
// of S into LDS f32 (b128 writes, zero borders), then each thread computes 8
// consecutive pixels via register windows (2x ds_read_b128 + 2x b32 / window).
template <int LVL>
__global__ __launch_bounds__(128) void k_gather(const u16* __restrict__ S,
    u16* __restrict__ feas, float* __restrict__ fea_s,
    const float* __restrict__ aac_b, const float* __restrict__ bn_g,
    const float* __restrict__ bn_b, const float* __restrict__ bn_m,
    const float* __restrict__ bn_v) {
  constexpr int W = LVL == 0 ? 128 : LVL == 1 ? 64 : LVL == 2 ? 32 : 16;
  constexpr int H = W;
  constexpr int RB = LVL == 0 ? 8 : LVL == 1 ? 16 : LVL == 2 ? 32 : 16;
  constexpr int RS = RB + 2;
  constexpr int LROW = W + 8;          // cols: [0..3]=0, 4..W+3=data, [W+4..W+7]=0
  constexpr int PS = RS * LROW;
  constexpr int HW = W * H;
  constexpr int CH = W / 4 + 2;        // b128 chunks per row incl 2 border chunks
  constexpr int XC = W / 8;            // 8-px chunks per row
  __shared__ alignas(16) float sm[9 * PS];
  __shared__ float red[2];
  const int tid = threadIdx.x;
  const int c = blockIdx.y;
  const int y0 = blockIdx.x * RB;

  // ---- staging ----
  for (int idx = tid; idx < 9 * RS * CH; idx += 128) {
    int s = idx / (RS * CH);
    int rem = idx - s * (RS * CH);
    int r = rem / CH, ch = rem - r * CH;
    int y = y0 - 1 + r;
    f32x4 v = {0.f, 0.f, 0.f, 0.f};
    if (ch >= 1 && ch <= W / 4 && y >= 0 && y < H) {
      u16x4 d = *(const u16x4*)(S + ((long)(s * 256 + c)) * HW + (long)y * W + (ch - 1) * 4);
      v[0] = b2f(d[0]); v[1] = b2f(d[1]); v[2] = b2f(d[2]); v[3] = b2f(d[3]);
    }
    *(f32x4*)&sm[s * PS + r * LROW + ch * 4] = v;
  }
  __syncthreads();

  // ---- per-channel BN constants ----
  float sc[5], sh[5];
#pragma unroll
  for (int m = 0; m < 5; ++m) {
    float g = bn_g[m * 256 + c], bb = bn_b[m * 256 + c];
    float mu = bn_m[m * 256 + c], vv = bn_v[m * 256 + c];
    float s = g * rsqrtf(vv + 1e-5f);
    sc[m] = s; sh[m] = bb - mu * s;
  }
  const float ab = aac_b[c];

  // ---- compute: thread -> (ro, xc) 8-px chunk ----
  const int ro = tid / XC, xc = tid - ro * XC;
  float lsum = 0.f;
  if (ro < RB) {
    float val[5][8];
#pragma unroll
    for (int m = 0; m < 5; ++m)
#pragma unroll
      for (int e = 0; e < 8; ++e) val[m][e] = ab;
    const int cb = xc * 8;             // window cols cb+3 .. cb+12
#pragma unroll
    for (int dy = 0; dy < 3; ++dy) {
#pragma unroll
      for (int s = 0; s < 9; ++s) {
        bool used = false;
#pragma unroll
        for (int m = 0; m < 5; ++m)
#pragma unroll
          for (int dx = 0; dx < 3; ++dx)
            if (ROT[m][dy * 3 + dx] == s) used = true;
        if (!used) continue;           // compile-time folded
        const float* rowp = &sm[s * PS + (ro + dy) * LROW + cb];
        float w[10];
        f32x4 va = *(const f32x4*)(rowp + 4);
        f32x4 vb = *(const f32x4*)(rowp + 8);
        w[0] = rowp[3];
        w[1] = va[0]; w[2] = va[1]; w[3] = va[2]; w[4] = va[3];
        w[5] = vb[0]; w[6] = vb[1]; w[7] = vb[2]; w[8] = vb[3];
        w[9] = rowp[12];
#pragma unroll
        for (int m = 0; m < 5; ++m)
#pragma unroll
          for (int dx = 0; dx < 3; ++dx)
            if (ROT[m][dy * 3 + dx] == s) {
#pragma unroll
              for (int e = 0; e < 8; ++e) val[m][e] += w[e + dx];
            }
      }
    }
    const int y = y0 + ro, x0 = xc * 8;
#pragma unroll
    for (int m = 0; m < 5; ++m) {
      u16x8 o;
#pragma unroll
      for (int e = 0; e < 8; ++e) {
        float f = fmaxf(val[m][e] * sc[m] + sh[m], 0.f);
        o[e] = f2b(f);
        lsum += f;
      }
      *(u16x8*)(feas + ((long)(m * 256 + c)) * HW + (long)y * W + x0) = o;
    }
  }
#pragma unroll
  for (int off = 32; off > 0; off >>= 1) lsum += __shfl_down(lsum, off);
  if ((tid & 63) == 0) red[tid >> 6] = lsum;
  __syncthreads();
  if (tid == 0) atomicAdd(&fea_s[c], red[0] + red[1]);
}

// ---------------- FC + softmax attention (1 block per level) ----------------
__global__ __launch_bounds__(1024) void k_fc_att(int lvl0, const float* __restrict__ fea_s,
                                                 const float* __restrict__ fc_w,
                                                 const float* __restrict__ fc_b,
                                                 const float* __restrict__ fcs_w,
                                                 const float* __restrict__ fcs_b,
                                                 float* __restrict__ att) {
  int lvl = lvl0 + blockIdx.x;
  const float inv_hw = 1.f / (float)(16384 >> (2 * lvl));
  const float* fs = fea_s + lvl * 256;
  const float* w1 = fc_w + (long)lvl * 128 * 256;
  const float* b1 = fc_b + lvl * 128;
  const float* w2 = fcs_w + (long)lvl * 5 * 256 * 128;
  const float* b2 = fcs_b + lvl * 5 * 256;
  float* at = att + lvl * 5 * 256;
  __shared__ float ss[256], zs[128], part[128][9], lg[1280];
  int tid = threadIdx.x;
  if (tid < 256) ss[tid] = fs[tid] * inv_hw;
  __syncthreads();
  {
    int d = tid >> 3, pq = tid & 7;
    const float* wr = w1 + d * 256;
    float acc = 0.f;
#pragma unroll 8
    for (int j = 0; j < 32; ++j) acc += ss[pq + 8 * j] * wr[pq + 8 * j];
    part[d][pq] = acc;
  }
  __syncthreads();
  if (tid < 128) {
    float z = b1[tid];
#pragma unroll
    for (int q = 0; q < 8; ++q) z += part[tid][q];
    zs[tid] = z;
  }
  __syncthreads();
  for (int idx = tid; idx < 1280; idx += 1024) {
    const f32x4* wv = (const f32x4*)(w2 + (long)idx * 128);
    float l = b2[idx];
#pragma unroll 8
    for (int d4 = 0; d4 < 32; ++d4) {
      f32x4 wq = wv[d4];
      l += zs[4 * d4] * wq[0] + zs[4 * d4 + 1] * wq[1] +
           zs[4 * d4 + 2] * wq[2] + zs[4 * d4 + 3] * wq[3];
    }
    lg[idx] = l;
  }
  __syncthreads();
  if (tid < 256) {
    float v[5], mx = -1e30f;
#pragma unroll
    for (int m = 0; m < 5; ++m) { v[m] = lg[m * 256 + tid]; mx = fmaxf(mx, v[m]); }
    float se = 0.f;
#pragma unroll
    for (int m = 0; m < 5; ++m) { v[m] = __expf(v[m] - mx); se += v[m]; }
    float inv = 1.f / se;
#pragma unroll
    for (int m = 0; m < 5; ++m) at[m * 256 + tid] = v[m] * inv;
  }
}

// ---------------- weighted combine ----------------
__global__ __launch_bounds__(256) void k_combine(const u16* __restrict__ feas,
                                                 const float* __restrict__ att,
                                                 float* __restrict__ out, int HW) {
  int idx = blockIdx.x * 256 + threadIdx.x;
  int hw8 = HW >> 3;
  int c = idx / hw8, p = (idx - c * hw8) << 3;
  float a[5];
#pragma unroll
  for (int m = 0; m < 5; ++m) a[m] = att[m * 256 + c];
  float o[8] = {};
#pragma unroll
  for (int m = 0; m < 5; ++m) {
    u16x8 v = *(const u16x8*)(feas + (long)(m * 256 + c) * HW + p);
#pragma unroll
    for (int e = 0; e < 8; ++e) o[e] += a[m] * b2f(v[e]);
  }
  float* op = out + (long)c * HW + p;
  f32x4 v0 = {o[0], o[1], o[2], o[3]};
  f32x4 v1 = {o[4], o[5], o[6], o[7]};
  *(f32x4*)op = v0;
  *(f32x4*)(op + 4) = v1;
}

// ---------------- host ----------------
extern "C" void kernel_launch(void* const* d_in, const int* in_sizes, int n_in,
                              void* d_out, int out_size, void* d_ws, size_t ws_size,
                              hipStream_t stream) {
  (void)n_in; (void)out_size;
  static const int HWs[4] = {16384, 4096, 1024, 256};
  static const int Ws[4]  = {128, 64, 32, 16};
  static const int Cin[4] = {256, 512, 1024, 2048};
  static const long out_off[4] = {0, 4194304, 5242880, 5505024};

  int xi[4], li[4];
  if (in_sizes[1] == 256 * 256) {
    for (int i = 0; i < 4; ++i) { xi[i] = 2 * i; li[i] = 2 * i + 1; }
  } else {
    for (int i = 0; i < 4; ++i) { xi[i] = i; li[i] = 4 + i; }
  }
  const float *x[4], *lw[4];
  for (int i = 0; i < 4; ++i) { x[i] = (const float*)d_in[xi[i]]; lw[i] = (const float*)d_in[li[i]]; }
  const float* lb    = (const float*)d_in[8];
  const float* aac_w = (const float*)d_in[9];
  const float* aac_b = (const float*)d_in[10];
  const float* bn_g  = (const float*)d_in[11];
  const float* bn_b  = (const float*)d_in[12];
  const float* bn_m  = (const float*)d_in[13];
  const float* bn_v  = (const float*)d_in[14];
  const float* fc_w  = (const float*)d_in[15];
  const float* fc_b  = (const float*)d_in[16];
  const float* fcs_w = (const float*)d_in[17];
  const float* fcs_b = (const float*)d_in[18];

  // fixed carve
  char* wp = (char*)d_ws;
  auto carve = [&](size_t bytes) { char* p = wp; wp += (bytes + 255) & ~(size_t)255; return p; };
  u16* xT[4];   for (int i = 0; i < 4; ++i) xT[i]   = (u16*)carve((size_t)HWs[i] * Cin[i] * 2);
  u16* lwb[4];  for (int i = 0; i < 4; ++i) lwb[i]  = (u16*)carve((size_t)256 * Cin[i] * 2);
  u16* latT[4]; for (int i = 0; i < 4; ++i) latT[i] = (u16*)carve((size_t)HWs[i] * 256 * 2);
  u16* W9[4];   for (int i = 0; i < 4; ++i) W9[i]   = (u16*)carve((size_t)2304 * 256 * 2);
  u16* Sb      = (u16*)carve((size_t)2304 * 16384 * 2);
  float* fea_s = (float*)carve(4 * 256 * 4);
  float* att   = (float*)carve(4 * 5 * 256 * 4);
  // feas: batched (per-level buffers, one fc_att launch) if ws allows
  size_t feas_bat = 0;
  for (int i = 0; i < 4; ++i) feas_bat += ((size_t)5 * 256 * HWs[i] * 2 + 255) & ~(size_t)255;
  size_t used_fixed = (size_t)(wp - (char*)d_ws);
  bool batched = used_fixed + feas_bat <= ws_size;
  u16* feas[4];
  if (batched) {
    for (int i = 0; i < 4; ++i) feas[i] = (u16*)carve((size_t)5 * 256 * HWs[i] * 2);
  } else {
    u16* shared_feas = (u16*)carve((size_t)5 * 256 * 16384 * 2);
    for (int i = 0; i < 4; ++i) feas[i] = shared_feas;
  }

  hipMemsetAsync(fea_s, 0, 4 * 256 * 4, stream);

  // batched prep
  k_cvt_all<<<3840, 256, 0, stream>>>(lw[0], lw[1], lw[2], lw[3],
                                      lwb[0], lwb[1], lwb[2], lwb[3]);
  k_transpose_all<<<7680, dim3(32, 8), 0, stream>>>(x[0], x[1], x[2], x[3],
                                                    xT[0], xT[1], xT[2], xT[3]);
  k_prep_w9_all<<<1024, 256, 0, stream>>>(aac_w, W9[0], W9[1], W9[2], W9[3]);

  // lateral 1x1 convs (transposed store + bias) and top-down pathway
  for (int i = 3; i >= 0; --i) {
    k_gemm<1><<<dim3(HWs[i] / 128, 2), 256, 0, stream>>>(lwb[i], xT[i], latT[i], lb + i * 256,
                                                         256, HWs[i], Cin[i], 256);
    if (i < 3)
      k_ups_add<<<HWs[i] / 8, 256, 0, stream>>>(latT[i], latT[i + 1], Ws[i], HWs[i]);
  }

  auto launch_gather = [&](int i) {
    const float* bg = bn_g + i * 1280; const float* bb = bn_b + i * 1280;
    const float* bm = bn_m + i * 1280; const float* bv = bn_v + i * 1280;
    const float* ab = aac_b + i * 256;
    float* fs = fea_s + i * 256;
    switch (i) {
      case 0: k_gather<0><<<dim3(16, 256), 128, 0, stream>>>(Sb, feas[0], fs, ab, bg, bb, bm, bv); break;
      case 1: k_gather<1><<<dim3(4, 256), 128, 0, stream>>>(Sb, feas[1], fs, ab, bg, bb, bm, bv); break;
      case 2: k_gather<2><<<dim3(1, 256), 128, 0, stream>>>(Sb, feas[2], fs, ab, bg, bb, bm, bv); break;
      case 3: k_gather<3><<<dim3(1, 256), 128, 0, stream>>>(Sb, feas[3], fs, ab, bg, bb, bm, bv); break;
    }
  };
  auto launch_fc = [&](int lvl0, int n) {
    k_fc_att<<<n, 1024, 0, stream>>>(lvl0, fea_s, fc_w, fc_b, fcs_w, fcs_b, att);
  };
  auto launch_combine = [&](int i) {
    k_combine<<<HWs[i] * 32 / 256, 256, 0, stream>>>(feas[i], att + i * 5 * 256,
                                                     (float*)d_out + out_off[i], HWs[i]);
  };

  if (batched) {
    for (int i = 0; i < 4; ++i) {
      k_gemm<0><<<dim3(HWs[i] / 128, 18), 256, 0, stream>>>(W9[i], latT[i], Sb, nullptr,
                                                            2304, HWs[i], 256, HWs[i]);
      launch_gather(i);
    }
    launch_fc(0, 4);
    for (int i = 0; i < 4; ++i) launch_combine(i);
  } else {
    for (int i = 0; i < 4; ++i) {
      k_gemm<0><<<dim3(HWs[i] / 128, 18), 256, 0, stream>>>(W9[i], latT[i], Sb, nullptr,
                                                            2304, HWs[i], 256, HWs[i]);
      launch_gather(i);
      launch_fc(i, 1);
      launch_combine(i);
    }
  }
}

// Round 4
// 305.858 us; speedup vs baseline: 1.8843x; 1.6039x over previous
//
#include <hip/hip_runtime.h>

// FPN_AAR: FPN lateral/top-down + AdaptiveAngleConv (5 rotated 3x3) + SK fusion.
// Rotations are permutations of one kernel -> compute 9 tap planes
// S[s] = W[:,:,s] @ lat (one GEMM), then each rotation is a 9-term shifted
// gather of the planes (5x FLOP reduction vs direct conv).
// R3: LDS-free shfl-based gather (fix 14% occupancy), all levels merged into
//     single launches (23 -> 9 kernels), split-K lateral GEMM (L3 tail).

typedef unsigned short u16;
typedef unsigned int   u32;
typedef __bf16 bf16x8 __attribute__((ext_vector_type(8)));
typedef float  f32x4  __attribute__((ext_vector_type(4)));
typedef u16    u16x8  __attribute__((ext_vector_type(8)));
typedef u16    u16x4  __attribute__((ext_vector_type(4)));

__device__ __forceinline__ u16 f2b(float f) {  // f32 -> bf16 RNE
  u32 u = __builtin_bit_cast(u32, f);
  return (u16)((u + 0x7fffu + ((u >> 16) & 1u)) >> 16);
}
__device__ __forceinline__ float b2f(u16 h) {
  u32 u = ((u32)h) << 16;
  return __builtin_bit_cast(float, u);
}

constexpr int ROT[5][9] = {
  {0,1,2,3,4,5,6,7,8},
  {3,0,1,6,4,2,7,8,5},
  {6,3,0,7,4,1,8,5,2},
  {7,6,3,8,4,0,5,2,1},
  {8,7,6,5,4,3,2,1,0}};

__device__ __forceinline__ void glds16(const u16* g, u16* l) {
  __builtin_amdgcn_global_load_lds((const __attribute__((address_space(1))) void*)g,
                                   (__attribute__((address_space(3))) void*)l, 16, 0, 0);
}

// ---------------- param structs (per-level pointers; by-value kernel args) ----
struct PrepP {
  const float* x[4]; u16* xT[4];
  const float* lw[4]; u16* lwb[4];
  const float* aac_w; u16* W9[4];
};
struct LatP { const u16* A[4]; const u16* B[4]; float* O[4]; };
struct FinP { const float* In[4]; const float* bias; u16* latT_all; };
struct SgP  { const u16* A[4]; const u16* B[4]; u16* C[4]; int bid_base; };
struct GatP { const u16* S[4]; u16* feas[4]; float* fea_s;
              const float* aac_b; const float* bn_g; const float* bn_b;
              const float* bn_m; const float* bn_v; int bid_base; };
struct CmbP { const u16* feas[4]; const float* att; float* out; int bid_base; };

// ---------------- merged prep: transpose + lw cvt + W9 permute ----------------
__global__ __launch_bounds__(256) void k_prep(PrepP P) {
  const int bid = blockIdx.x;
  const int tid = threadIdx.x;
  if (bid < 7680) {              // transpose f32 [C][P] -> bf16 [P][C]
    __shared__ u16 t[32][33];
    int lvl, local;
    if (bid < 4096)      { lvl = 0; local = bid; }
    else if (bid < 6144) { lvl = 1; local = bid - 4096; }
    else if (bid < 7168) { lvl = 2; local = bid - 6144; }
    else                 { lvl = 3; local = bid - 7168; }
    const float* src = P.x[lvl];
    u16* dst = P.xT[lvl];
    const int Pp = 16384 >> (2 * lvl);
    const int C = 256 << lvl;
    const int pbs = 9 - 2 * lvl;          // log2(P/32)
    int bx = local & ((1 << pbs) - 1), by = local >> pbs;
    int p0 = bx * 32, c0 = by * 32;
    int tx = tid & 31, ty = tid >> 5;
#pragma unroll
    for (int j = 0; j < 4; ++j)
      t[ty + 8 * j][tx] = f2b(src[(long)(c0 + ty + 8 * j) * Pp + p0 + tx]);
    __syncthreads();
#pragma unroll
    for (int j = 0; j < 4; ++j)
      dst[(long)(p0 + ty + 8 * j) * C + c0 + tx] = t[tx][ty + 8 * j];
  } else if (bid < 11520) {      // lw f32 -> bf16
    int i = (bid - 7680) * 256 + tid;
    const float* src; u16* dst; int off;
    if (i < 65536)       { src = P.lw[0]; dst = P.lwb[0]; off = i; }
    else if (i < 196608) { src = P.lw[1]; dst = P.lwb[1]; off = i - 65536; }
    else if (i < 458752) { src = P.lw[2]; dst = P.lwb[2]; off = i - 196608; }
    else                 { src = P.lw[3]; dst = P.lwb[3]; off = i - 458752; }
    dst[off] = f2b(src[off]);
  } else {                       // aac_w [4][256][256][9] -> W9 [(s*256+oc)][ic]
    int gid = (bid - 11520) * 256 + tid;
    int lvl = gid >> 16, idx = gid & 65535;
    u16* out = P.W9[lvl];
    const float* src = P.aac_w + (long)lvl * 589824 + (long)idx * 9;
    int oc = idx >> 8, ic = idx & 255;
    float v[9];
#pragma unroll
    for (int s = 0; s < 9; ++s) v[s] = src[s];
#pragma unroll
    for (int s = 0; s < 9; ++s) out[(long)((s << 8) + oc) * 256 + ic] = f2b(v[s]);
  }
}

// ---------------- lateral GEMM, split-K (chunk = 256), f32 chunk buffers ------
// level l: M=256, N=HW, K=256<<l, chunks=1<<l. Output transposed [p][oc] f32.
__global__ __launch_bounds__(256) void k_lat(LatP P) {
  constexpr int base[5] = {0, 256, 384, 448, 480};
  constexpr int NTS[4] = {7, 5, 3, 1};   // log2(N/128)
  int bid = blockIdx.x;
  int lvl = 0;
  while (bid >= base[lvl + 1]) ++lvl;
  int local = bid - base[lvl];
  const int nts = NTS[lvl];
  const int kc = local >> (nts + 1);
  const int r = local & ((2 << nts) - 1);
  const int by = r >> nts, bx = r & ((1 << nts) - 1);
  const int N = 16384 >> (2 * lvl);
  const long KF = 256 << lvl;
  const long kq = (long)kc * 256;
  const u16* A = P.A[lvl];
  const u16* B = P.B[lvl];
  float* O = P.O[lvl] + (long)kc * N * 256;

  __shared__ alignas(16) u16 As[128 * 32];
  __shared__ alignas(16) u16 Bs[128 * 32];
  const int tid = threadIdx.x;
  const int wid = tid >> 6, lane = tid & 63;
  const int wr = wid >> 1, wc = wid & 1;
  const int m0 = by * 128, n0 = bx * 128;
  const int lr = lane & 15, lk = lane >> 4;
  f32x4 acc[4][4] = {};
  const int t0 = wid * 2;
  const int srow = lane >> 2, scol = (lane & 3) * 8;
  const u16* gA0 = A + (long)(m0 + t0 * 16 + srow) * KF + kq + scol;
  const u16* gA1 = A + (long)(m0 + t0 * 16 + 16 + srow) * KF + kq + scol;
  const u16* gB0 = B + (long)(n0 + t0 * 16 + srow) * KF + kq + scol;
  const u16* gB1 = B + (long)(n0 + t0 * 16 + 16 + srow) * KF + kq + scol;
  u16* lA0 = As + t0 * 512;
  u16* lA1 = As + t0 * 512 + 512;
  u16* lB0 = Bs + t0 * 512;
  u16* lB1 = Bs + t0 * 512 + 512;
  for (int kt = 0; kt < 256; kt += 32) {
    glds16(gA0 + kt, lA0);
    glds16(gA1 + kt, lA1);
    glds16(gB0 + kt, lB0);
    glds16(gB1 + kt, lB1);
    __syncthreads();
    bf16x8 af[4], bfr[4];
#pragma unroll
    for (int m = 0; m < 4; ++m)
      af[m] = *(const bf16x8*)(As + (wr * 64 + m * 16 + lr) * 32 + lk * 8);
#pragma unroll
    for (int n = 0; n < 4; ++n)
      bfr[n] = *(const bf16x8*)(Bs + (wc * 64 + n * 16 + lr) * 32 + lk * 8);
#pragma unroll
    for (int m = 0; m < 4; ++m)
#pragma unroll
      for (int n = 0; n < 4; ++n)
        acc[m][n] = __builtin_amdgcn_mfma_f32_16x16x32_bf16(af[m], bfr[n], acc[m][n], 0, 0, 0);
    __syncthreads();
  }
#pragma unroll
  for (int m = 0; m < 4; ++m) {
    int row = m0 + wr * 64 + m * 16 + lk * 4;   // oc
#pragma unroll
    for (int n = 0; n < 4; ++n) {
      int col = n0 + wc * 64 + n * 16 + lr;     // pixel
      *(f32x4*)(O + (long)col * 256 + row) = acc[m][n];
    }
  }
}

// ---------------- finalize: sum chunks + bias -> latT bf16 --------------------
__global__ __launch_bounds__(256) void k_fin(FinP P) {
  constexpr long eb[5] = {0, 4194304, 5242880, 5505024, 5570560};  // latT elem offsets
  long idx = ((long)blockIdx.x * 256 + threadIdx.x) * 8;
  int lvl = 0;
  while (idx >= eb[lvl + 1]) ++lvl;
  long local = idx - eb[lvl];
  const int chunks = 1 << lvl;
  const long cstride = (long)(16384 >> (2 * lvl)) * 256;
  const float* in = P.In[lvl] + local;
  f32x4 s0 = {0.f, 0.f, 0.f, 0.f}, s1 = {0.f, 0.f, 0.f, 0.f};
  for (int k = 0; k < chunks; ++k) {
    s0 += *(const f32x4*)(in + k * cstride);
    s1 += *(const f32x4*)(in + k * cstride + 4);
  }
  int oc = (int)(local & 255);
  const float* bias = P.bias + lvl * 256 + oc;
  f32x4 b0 = *(const f32x4*)bias;
  f32x4 b1 = *(const f32x4*)(bias + 4);
  u16x8 o;
#pragma unroll
  for (int i = 0; i < 4; ++i) { o[i] = f2b(s0[i] + b0[i]); o[4 + i] = f2b(s1[i] + b1[i]); }
  *(u16x8*)(P.latT_all + idx) = o;
}

// ---------------- upsample-add: dst [HW][256] += up2(src [HW/4][256]) ---------
__global__ void k_ups_add(u16* __restrict__ dst, const u16* __restrict__ src, int W, int HW) {
  int idx = blockIdx.x * 256 + threadIdx.x;
  int p = idx >> 5, c8 = (idx & 31) << 3;
  if (p >= HW) return;
  int y = p / W, x = p - y * W;
  int sp = (y >> 1) * (W >> 1) + (x >> 1);
  u16x8 d = *(const u16x8*)(dst + (long)p * 256 + c8);
  u16x8 s = *(const u16x8*)(src + (long)sp * 256 + c8);
  u16x8 o;
#pragma unroll
  for (int e = 0; e < 8; ++e) o[e] = f2b(b2f(d[e]) + b2f(s[e]));
  *(u16x8*)(dst + (long)p * 256 + c8) = o;
}

// ---------------- S-GEMM (merged levels): Sb[lvl] = W9[lvl] @ latT[lvl]^T -----
__global__ __launch_bounds__(256) void k_sgemm(SgP P) {
  constexpr int base[5] = {0, 2304, 2880, 3024, 3060};
  constexpr int NTS[4] = {7, 5, 3, 1};
  int bid = blockIdx.x + P.bid_base;
  int lvl = 0;
  while (bid >= base[lvl + 1]) ++lvl;
  int local = bid - base[lvl];
  const int nts = NTS[lvl];
  const int by = local >> nts, bx = local & ((1 << nts) - 1);
  const int N = 16384 >> (2 * lvl);
  const u16* A = P.A[lvl];       // [2304][256]
  const u16* B = P.B[lvl];       // [N][256]
  u16* C = P.C[lvl];             // [2304][N]

  __shared__ alignas(16) u16 As[128 * 32];
  __shared__ alignas(16) u16 Bs[128 * 32];
  const int tid = threadIdx.x;
  const int wid = tid >> 6, lane = tid & 63;
  const int wr = wid >> 1, wc = wid & 1;
  const int m0 = by * 128, n0 = bx * 128;
  const int lr = lane & 15, lk = lane >> 4;
  f32x4 acc[4][4] = {};
  const int t0 = wid * 2;
  const int srow = lane >> 2, scol = (lane & 3) * 8;
  const u16* gA0 = A + (long)(m0 + t0 * 16 + srow) * 256 + scol;
  const u16* gA1 = A + (long)(m0 + t0 * 16 + 16 + srow) * 256 + scol;
  const u16* gB0 = B + (long)(n0 + t0 * 16 + srow) * 256 + scol;
  const u16* gB1 = B + (long)(n0 + t0 * 16 + 16 + srow) * 256 + scol;
  u16* lA0 = As + t0 * 512;
  u16* lA1 = As + t0 * 512 + 512;
  u16* lB0 = Bs + t0 * 512;
  u16* lB1 = Bs + t0 * 512 + 512;
  for (int kt = 0; kt < 256; kt += 32) {
    glds16(gA0 + kt, lA0);
    glds16(gA1 + kt, lA1);
    glds16(gB0 + kt, lB0);
    glds16(gB1 + kt, lB1);
    __syncthreads();
    bf16x8 af[4], bfr[4];
#pragma unroll
    for (int m = 0; m < 4; ++m)
      af[m] = *(const bf16x8*)(As + (wr * 64 + m * 16 + lr) * 32 + lk * 8);
#pragma unroll
    for (int n = 0; n < 4; ++n)
      bfr[n] = *(const bf16x8*)(Bs + (wc * 64 + n * 16 + lr) * 32 + lk * 8);
#pragma unroll
    for (int m = 0; m < 4; ++m)
#pragma unroll
      for (int n = 0; n < 4; ++n)
        acc[m][n] = __builtin_amdgcn_mfma_f32_16x16x32_bf16(af[m], bfr[n], acc[m][n], 0, 0, 0);
    __syncthreads();
  }
#pragma unroll
  for (int m = 0; m < 4; ++m) {
    int row = m0 + wr * 64 + m * 16 + lk * 4;
#pragma unroll
    for (int n = 0; n < 4; ++n) {
      int col = n0 + wc * 64 + n * 16 + lr;
#pragma unroll
      for (int i = 0; i < 4; ++i)
        C[(long)(row + i) * N + col] = f2b(acc[m][n][i]);
    }
  }
}

// ---------------- gather + BN + ReLU + channel-sum (LDS-free, shfl borders) ---
template <int LVL>
__device__ __forceinline__ void gather_impl(int local_bid, const GatP& P) {
  constexpr int W = 128 >> LVL, H = W, HW = W * W;
  constexpr int XC = W / 8;
  constexpr int XS = 4 - LVL;          // log2 XC
  constexpr int HS = 7 - LVL;          // log2 H
  const int tid = threadIdx.x;
  const int gid = local_bid * 256 + tid;
  const int xc = gid & (XC - 1);
  const int rem = gid >> XS;
  const int y = rem & (H - 1);
  const int c = rem >> HS;
  const u16* S = P.S[LVL];

  float sc[5], sh[5];
#pragma unroll
  for (int m = 0; m < 5; ++m) {
    float g = P.bn_g[LVL * 1280 + m * 256 + c], bb = P.bn_b[LVL * 1280 + m * 256 + c];
    float mu = P.bn_m[LVL * 1280 + m * 256 + c], vv = P.bn_v[LVL * 1280 + m * 256 + c];
    float s = g * rsqrtf(vv + 1e-5f);
    sc[m] = s; sh[m] = bb - mu * s;
  }
  const float ab = P.aac_b[LVL * 256 + c];
  float val[5][8];
#pragma unroll
  for (int m = 0; m < 5; ++m)
#pragma unroll
    for (int e = 0; e < 8; ++e) val[m][e] = ab;

#pragma unroll
  for (int dy = 0; dy < 3; ++dy) {
    const int row = y + dy - 1;
    const bool inr = (unsigned)row < (unsigned)H;
    const u16* Srow = S + (long)row * W + (xc << 3);
#pragma unroll
    for (int s = 0; s < 9; ++s) {
      bool used = false;
#pragma unroll
      for (int m = 0; m < 5; ++m)
#pragma unroll
        for (int dx = 0; dx < 3; ++dx)
          if (ROT[m][dy * 3 + dx] == s) used = true;
      if (!used) continue;             // compile-time folded
      u16x8 v = {0, 0, 0, 0, 0, 0, 0, 0};
      if (inr) v = *(const u16x8*)(Srow + (long)(s * 256 + c) * HW);
      float f[8];
#pragma unroll
      for (int j = 0; j < 8; ++j) f[j] = b2f(v[j]);
      float left = __shfl_up(f[7], 1);
      float right = __shfl_down(f[0], 1);
      if (xc == 0) left = 0.f;
      if (xc == XC - 1) right = 0.f;
      float wv[10];
      wv[0] = left;
#pragma unroll
      for (int j = 0; j < 8; ++j) wv[j + 1] = f[j];
      wv[9] = right;
#pragma unroll
      for (int m = 0; m < 5; ++m)
#pragma unroll
        for (int dx = 0; dx < 3; ++dx)
          if (ROT[m][dy * 3 + dx] == s) {
#pragma unroll
            for (int e = 0; e < 8; ++e) val[m][e] += wv[e + dx];
          }
    }
  }

  float lsum = 0.f;
  u16* F = P.feas[LVL];
#pragma unroll
  for (int m = 0; m < 5; ++m) {
    u16x8 o;
#pragma unroll
    for (int e = 0; e < 8; ++e) {
      float r = fmaxf(val[m][e] * sc[m] + sh[m], 0.f);
      o[e] = f2b(r);
      lsum += r;
    }
    *(u16x8*)(F + (long)(m * 256 + c) * HW + (long)y * W + (xc << 3)) = o;
  }
  constexpr int RG = (LVL == 3) ? 32 : 64;   // all lanes in group share c
#pragma unroll
  for (int off = RG >> 1; off > 0; off >>= 1) lsum += __shfl_xor(lsum, off);
  if ((tid & (RG - 1)) == 0) atomicAdd(P.fea_s + LVL * 256 + c, lsum);
}

__global__ __launch_bounds__(256) void k_gather(GatP P) {
  int bid = blockIdx.x + P.bid_base;
  if (bid < 2048) gather_impl<0>(bid, P);
  else if (bid < 2560) gather_impl<1>(bid - 2048, P);
  else if (bid < 2688) gather_impl<2>(bid - 2560, P);
  else gather_impl<3>(bid - 2688, P);
}

// ---------------- FC + softmax attention (1 block / level) ----------------
__global__ __launch_bounds__(1024) void k_fc_att(int lvl0, const float* __restrict__ fea_s,
                                                 const float* __restrict__ fc_w,
                                                 const float* __restrict__ fc_b,
                                                 const float* __restrict__ fcs_w,
                                                 const float* __restrict__ fcs_b,
                                                 float* __restrict__ att) {
  int lvl = lvl0 + blockIdx.x;
  const float inv_hw = 1.f / (float)(16384 >> (2 * lvl));
  const float* fs = fea_s + lvl * 256;
  const float* w1 = fc_w + (long)lvl * 128 * 256;
  const float* b1 = fc_b + lvl * 128;
  const float* w2 = fcs_w + (long)lvl * 5 * 256 * 128;
  const float* b2 = fcs_b + lvl * 5 * 256;
  float* at = att + lvl * 5 * 256;
  __shared__ float ss[256], zs[128], part[128][9], lg[1280];
  int tid = threadIdx.x;
  if (tid < 256) ss[tid] = fs[tid] * inv_hw;
  __syncthreads();
  {
    int d = tid >> 3, pq = tid & 7;
    const float* wr = w1 + d * 256;
    float acc = 0.f;
#pragma unroll 8
    for (int j = 0; j < 32; ++j) acc += ss[pq + 8 * j] * wr[pq + 8 * j];
    part[d][pq] = acc;
  }
  __syncthreads();
  if (tid < 128) {
    float z = b1[tid];
#pragma unroll
    for (int q = 0; q < 8; ++q) z += part[tid][q];
    zs[tid] = z;
  }
  __syncthreads();
  for (int idx = tid; idx < 1280; idx += 1024) {
    const f32x4* wv = (const f32x4*)(w2 + (long)idx * 128);
    float l = b2[idx];
#pragma unroll 8
    for (int d4 = 0; d4 < 32; ++d4) {
      f32x4 wq = wv[d4];
      l += zs[4 * d4] * wq[0] + zs[4 * d4 + 1] * wq[1] +
           zs[4 * d4 + 2] * wq[2] + zs[4 * d4 + 3] * wq[3];
    }
    lg[idx] = l;
  }
  __syncthreads();
  if (tid < 256) {
    float v[5], mx = -1e30f;
#pragma unroll
    for (int m = 0; m < 5; ++m) { v[m] = lg[m * 256 + tid]; mx = fmaxf(mx, v[m]); }
    float se = 0.f;
#pragma unroll
    for (int m = 0; m < 5; ++m) { v[m] = __expf(v[m] - mx); se += v[m]; }
    float inv = 1.f / se;
#pragma unroll
    for (int m = 0; m < 5; ++m) at[m * 256 + tid] = v[m] * inv;
  }
}

// ---------------- weighted combine (merged levels) ----------------
__global__ __launch_bounds__(256) void k_combine(CmbP P) {
  constexpr int base[5] = {0, 2048, 2560, 2688, 2720};
  constexpr long ooff[4] = {0, 4194304, 5242880, 5505024};
  int bid = blockIdx.x + P.bid_base;
  int lvl = 0;
  while (bid >= base[lvl + 1]) ++lvl;
  int local = bid - base[lvl];
  const int HW = 16384 >> (2 * lvl);
  const int hw8s = 11 - 2 * lvl;       // log2(HW/8)
  int idx = local * 256 + threadIdx.x;
  int c = idx >> hw8s;
  int p = (idx & ((1 << hw8s) - 1)) << 3;
  const u16* feas = P.feas[lvl];
  const float* att = P.att + lvl * 1280;
  float* out = P.out + ooff[lvl];
  float a[5];
#pragma unroll
  for (int m = 0; m < 5; ++m) a[m] = att[m * 256 + c];
  float o[8] = {};
#pragma unroll
  for (int m = 0; m < 5; ++m) {
    u16x8 v = *(const u16x8*)(feas + (long)(m * 256 + c) * HW + p);
#pragma unroll
    for (int e = 0; e < 8; ++e) o[e] += a[m] * b2f(v[e]);
  }
  float* op = out + (long)c * HW + p;
  f32x4 v0 = {o[0], o[1], o[2], o[3]};
  f32x4 v1 = {o[4], o[5], o[6], o[7]};
  *(f32x4*)op = v0;
  *(f32x4*)(op + 4) = v1;
}

// ---------------- host ----------------
extern "C" void kernel_launch(void* const* d_in, const int* in_sizes, int n_in,
                              void* d_out, int out_size, void* d_ws, size_t ws_size,
                              hipStream_t stream) {
  (void)n_in; (void)out_size;
  static const int HWs[4] = {16384, 4096, 1024, 256};
  static const int Ws[4]  = {128, 64, 32, 16};
  static const int Cin[4] = {256, 512, 1024, 2048};
  static const long LToff[4] = {0, 4194304, 5242880, 5505024};
  static const long SBoff[4] = {0, 37748736, 47185920, 49545216};  // 2304*HW cumsum
  static const long Foff[4]  = {0, 20971520, 26214400, 27525120};  // 1280*HW cumsum
  static const long Loff[4]  = {0, 4194304, 6291456, 7340032};     // f32 chunk bufs

  int xi[4], li[4];
  if (in_sizes[1] == 256 * 256) {
    for (int i = 0; i < 4; ++i) { xi[i] = 2 * i; li[i] = 2 * i + 1; }
  } else {
    for (int i = 0; i < 4; ++i) { xi[i] = i; li[i] = 4 + i; }
  }
  const float *x[4], *lw[4];
  for (int i = 0; i < 4; ++i) { x[i] = (const float*)d_in[xi[i]]; lw[i] = (const float*)d_in[li[i]]; }
  const float* lb    = (const float*)d_in[8];
  const float* aac_w = (const float*)d_in[9];
  const float* aac_b = (const float*)d_in[10];
  const float* bn_g  = (const float*)d_in[11];
  const float* bn_b  = (const float*)d_in[12];
  const float* bn_m  = (const float*)d_in[13];
  const float* bn_v  = (const float*)d_in[14];
  const float* fc_w  = (const float*)d_in[15];
  const float* fc_b  = (const float*)d_in[16];
  const float* fcs_w = (const float*)d_in[17];
  const float* fcs_b = (const float*)d_in[18];

  char* wp = (char*)d_ws;
  auto carve = [&](size_t bytes) { char* p = wp; wp += (bytes + 255) & ~(size_t)255; return p; };
  u16* xT[4];  for (int i = 0; i < 4; ++i) xT[i]  = (u16*)carve((size_t)HWs[i] * Cin[i] * 2);
  u16* lwb[4]; for (int i = 0; i < 4; ++i) lwb[i] = (u16*)carve((size_t)256 * Cin[i] * 2);
  u16* latT_all = (u16*)carve((size_t)5570560 * 2);
  u16* W9[4];  for (int i = 0; i < 4; ++i) W9[i]  = (u16*)carve((size_t)2304 * 256 * 2);
  float* fea_s = (float*)carve(4 * 256 * 4);
  float* att   = (float*)carve(4 * 5 * 256 * 4);
  size_t fixed = (size_t)(wp - (char*)d_ws);
  const size_t szSbAll   = (size_t)50135040 * 2;   // per-level Sb, all levels
  const size_t szFeasAll = (size_t)27852800 * 2;   // per-level feas
  const size_t szSbSh    = (size_t)37748736 * 2;   // L0-sized shared Sb
  const size_t szFeasSh  = (size_t)20971520 * 2;   // L0-sized shared feas
  bool tierA = fixed + szSbAll + szFeasAll + 1024 <= ws_size;

  u16* Sb;     // also aliased as f32 split-K chunk buffers (used before Sb writes)
  u16* feasB;
  if (tierA) { Sb = (u16*)carve(szSbAll); feasB = (u16*)carve(szFeasAll); }
  else       { Sb = (u16*)carve(szSbSh);  feasB = (u16*)carve(szFeasSh); }
  float* latF32 = (float*)Sb;

  hipMemsetAsync(fea_s, 0, 4 * 256 * 4, stream);

  // --- prep ---
  PrepP pp;
  for (int i = 0; i < 4; ++i) {
    pp.x[i] = x[i]; pp.xT[i] = xT[i]; pp.lw[i] = lw[i]; pp.lwb[i] = lwb[i]; pp.W9[i] = W9[i];
  }
  pp.aac_w = aac_w;
  k_prep<<<12544, 256, 0, stream>>>(pp);

  // --- lateral GEMM (split-K) + finalize + top-down ---
  LatP lp;
  for (int i = 0; i < 4; ++i) { lp.A[i] = lwb[i]; lp.B[i] = xT[i]; lp.O[i] = latF32 + Loff[i]; }
  k_lat<<<480, 256, 0, stream>>>(lp);
  FinP fp;
  for (int i = 0; i < 4; ++i) fp.In[i] = latF32 + Loff[i];
  fp.bias = lb; fp.latT_all = latT_all;
  k_fin<<<2720, 256, 0, stream>>>(fp);
  for (int i = 2; i >= 0; --i)
    k_ups_add<<<HWs[i] / 8, 256, 0, stream>>>(latT_all + LToff[i], latT_all + LToff[i + 1],
                                              Ws[i], HWs[i]);

  static const int cnt_s[4] = {2304, 576, 144, 36};
  static const int base_s[4] = {0, 2304, 2880, 3024};
  static const int cnt_g[4] = {2048, 512, 128, 32};
  static const int base_g[4] = {0, 2048, 2560, 2688};

  SgP sp;
  GatP gp;
  CmbP cp;
  for (int i = 0; i < 4; ++i) {
    sp.A[i] = W9[i];
    sp.B[i] = latT_all + LToff[i];
    sp.C[i] = tierA ? Sb + SBoff[i] : Sb;
    gp.S[i] = sp.C[i];
    gp.feas[i] = tierA ? feasB + Foff[i] : feasB;
    cp.feas[i] = gp.feas[i];
  }
  gp.fea_s = fea_s;
  gp.aac_b = aac_b; gp.bn_g = bn_g; gp.bn_b = bn_b; gp.bn_m = bn_m; gp.bn_v = bn_v;
  cp.att = att; cp.out = (float*)d_out;

  if (tierA) {
    sp.bid_base = 0; gp.bid_base = 0; cp.bid_base = 0;
    k_sgemm<<<3060, 256, 0, stream>>>(sp);
    k_gather<<<2720, 256, 0, stream>>>(gp);
    k_fc_att<<<4, 1024, 0, stream>>>(0, fea_s, fc_w, fc_b, fcs_w, fcs_b, att);
    k_combine<<<2720, 256, 0, stream>>>(cp);
  } else {
    for (int i = 0; i < 4; ++i) {
      sp.bid_base = base_s[i];
      k_sgemm<<<cnt_s[i], 256, 0, stream>>>(sp);
      gp.bid_base = base_g[i];
      k_gather<<<cnt_g[i], 256, 0, stream>>>(gp);
      k_fc_att<<<1, 1024, 0, stream>>>(i, fea_s, fc_w, fc_b, fcs_w, fcs_b, att);
      cp.bid_base = base_g[i];
      k_combine<<<cnt_g[i], 256, 0, stream>>>(cp);
    }
  }
}